// Round 15
// baseline (229.017 us; speedup 1.0000x reference)
//
#include <hip/hip_runtime.h>

#define IW 512
#define IH 512
#define NPIX (IW * IH)
#define NSHARD 8
#define EMPTY_KEY 0xFFFFFFFFFFFFFFFFull

__global__ void init_shards(unsigned long long* __restrict__ kb) {
    int i = blockIdx.x * blockDim.x + threadIdx.x;
    if (i < NSHARD * NPIX) kb[i] = EMPTY_KEY;
}

// f32 mirror of the XLA-on-gfx950 compiled reference graph (FROZEN — passed
// absmax 0.0 in rounds 8-14):
//  - divisions lowered as a * v_rcp_f32(b)
//  - r2 contracted as fma(dx,dx, dy*dy)
//  - all other ops singly-rounded (contract(off)); matmul terms exact.
__device__ __forceinline__ bool project_voxel(
        float x, float y, float z0,
        const float* __restrict__ m1, const float* __restrict__ m2,
        float& px, float& py, float& vz) {
#pragma clang fp contract(off)
    float vh0 = ((x * m1[0]  + y * m1[4])  + z0 * m1[8])  + m1[12];
    float vh1 = ((x * m1[1]  + y * m1[5])  + z0 * m1[9])  + m1[13];
    float vh2 = ((x * m1[2]  + y * m1[6])  + z0 * m1[10]) + m1[14];
    float vh3 = ((x * m1[3]  + y * m1[7])  + z0 * m1[11]) + m1[15];

    float wv  = (fabsf(vh3) > 1e-8f) ? vh3 : 1.0f;
    float rwv = __builtin_amdgcn_rcpf(wv);
    float vx  = vh0 * rwv;
    float vy  = vh1 * rwv;
    vz        = vh2 * rwv;

    float cl0 = ((vx * m2[0] + vy * m2[4]) + vz * m2[8])  + m2[12];
    float cl1 = ((vx * m2[1] + vy * m2[5]) + vz * m2[9])  + m2[13];
    float cl3 = ((vx * m2[3] + vy * m2[7]) + vz * m2[11]) + m2[15];

    if (!(fabsf(cl3) > 1e-8f)) return false;  // valid: |w| > 1e-8 (rejects NaN)
    if (!(vz > 1e-6f)) return false;          // valid: z > 1e-6  (rejects NaN)

    float rw   = __builtin_amdgcn_rcpf(cl3);
    float ndcx = cl0 * rw;
    float ndcy = cl1 * rw;
    px = ((ndcx + 1.0f) * 0.5f) * (float)IW;
    py = ((ndcy + 1.0f) * 0.5f) * (float)IH;
    return true;
}

// XCD-sharded splat, round-15 variant: voxel stream loaded NON-TEMPORALLY
// (nt -> no L2 allocate / evict-first) so the XCD's own 2 MB shard stays
// resident in its 4 MB L2. r14 PMC showed the workgroup-scope atomics DO
// execute in the local L2 (FETCH grew to 176 MB = lines pulled into L2,
// then evicted by the 48 MB voxel stream -> writeback+refetch churn).
// Single-writer-XCD per shard -> no cross-XCD coherence needed; dispatch
// boundary flushes dirty shard lines before the merge kernel.
// Pre-check load is safe: shard keys only decrease; stale >= current, so
// skipping when key >= observed can never drop a winner.
__global__ __launch_bounds__(256) void splat_sharded(
        const float* __restrict__ vox, const float* __restrict__ m1,
        const float* __restrict__ m2, unsigned long long* __restrict__ shards,
        int N) {
#pragma clang fp contract(off)
    int n = blockIdx.x * blockDim.x + threadIdx.x;
    if (n >= N) return;

    unsigned xcc;
    asm("s_getreg_b32 %0, hwreg(HW_REG_XCC_ID, 0, 4)" : "=s"(xcc));
    unsigned long long* kb = shards + (size_t)(xcc & (NSHARD - 1)) * NPIX;

    float x  = __builtin_nontemporal_load(vox + n * 6 + 0);
    float y  = __builtin_nontemporal_load(vox + n * 6 + 1);
    float z0 = __builtin_nontemporal_load(vox + n * 6 + 2);

    float px, py, vz;
    if (!project_voxel(x, y, z0, m1, m2, px, py, vz)) return;

    float fx = floorf(px);
    float fy = floorf(py);
    if (!(fx >= -1.0f && fx <= (float)IW && fy >= -1.0f && fy <= (float)IH))
        return;

    unsigned long long zhi = ((unsigned long long)__float_as_uint(vz)) << 32;
    unsigned basepid = (unsigned)n * 9u;

    for (int oy = -1; oy <= 1; ++oy) {
        for (int ox = -1; ox <= 1; ++ox) {
            float ixf = fx + (float)ox;
            float iyf = fy + (float)oy;
            if (!(ixf >= 0.0f && ixf < (float)IW &&
                  iyf >= 0.0f && iyf < (float)IH)) continue;
            float dx = (ixf + 0.5f) - px;
            float dy = (iyf + 0.5f) - py;
            float r2 = fmaf(dx, dx, dy * dy);   // frozen contraction form
            if (!(r2 <= 1.0f)) continue;
            int pix = (int)iyf * IW + (int)ixf;
            unsigned pid = basepid + (unsigned)((oy + 1) * 3 + (ox + 1));
            unsigned long long key = zhi | (unsigned long long)pid;
            if (key < kb[pix]) {                // L2-resident local shard
                __hip_atomic_fetch_min(&kb[pix], key,
                                       __ATOMIC_RELAXED,
                                       __HIP_MEMORY_SCOPE_WORKGROUP);
            }
        }
    }
}

__global__ void merge_resolve(const unsigned long long* __restrict__ shards,
                              const float* __restrict__ vox,
                              float* __restrict__ out) {
    int p = blockIdx.x * blockDim.x + threadIdx.x;
    if (p >= NPIX) return;
    unsigned long long key = EMPTY_KEY;
#pragma unroll
    for (int s = 0; s < NSHARD; ++s) {
        unsigned long long k = shards[(size_t)s * NPIX + p];  // coalesced
        key = (k < key) ? k : key;
    }
    float r = 0.0f, g = 0.0f, b = 0.0f;
    if (key != EMPTY_KEY) {
        unsigned n = (unsigned)(key & 0xFFFFFFFFull) / 9u;
        r = vox[n * 6 + 3];
        g = vox[n * 6 + 4];
        b = vox[n * 6 + 5];
    }
    out[p * 3 + 0] = r;
    out[p * 3 + 1] = g;
    out[p * 3 + 2] = b;
}

// -------- fallback (tiny ws): proven round-8 style single blind pass -------
__global__ void init_bufs(unsigned long long* __restrict__ kb) {
    int i = blockIdx.x * blockDim.x + threadIdx.x;
    if (i < NPIX) kb[i] = EMPTY_KEY;
}

__global__ __launch_bounds__(256) void splat_flat(
        const float* __restrict__ vox, const float* __restrict__ m1,
        const float* __restrict__ m2, unsigned long long* __restrict__ kb,
        int N) {
#pragma clang fp contract(off)
    int n = blockIdx.x * blockDim.x + threadIdx.x;
    if (n >= N) return;
    float px, py, vz;
    if (!project_voxel(vox[n*6], vox[n*6+1], vox[n*6+2], m1, m2, px, py, vz)) return;
    float fx = floorf(px), fy = floorf(py);
    if (!(fx >= -1.0f && fx <= (float)IW && fy >= -1.0f && fy <= (float)IH)) return;
    unsigned long long zhi = ((unsigned long long)__float_as_uint(vz)) << 32;
    unsigned basepid = (unsigned)n * 9u;
    for (int oy = -1; oy <= 1; ++oy)
        for (int ox = -1; ox <= 1; ++ox) {
            float ixf = fx + (float)ox, iyf = fy + (float)oy;
            if (!(ixf >= 0.0f && ixf < (float)IW && iyf >= 0.0f && iyf < (float)IH)) continue;
            float dx = (ixf + 0.5f) - px, dy = (iyf + 0.5f) - py;
            float r2 = fmaf(dx, dx, dy * dy);
            if (!(r2 <= 1.0f)) continue;
            int pix = (int)iyf * IW + (int)ixf;
            unsigned long long key = zhi | (unsigned long long)(basepid + (unsigned)((oy+1)*3+(ox+1)));
            if (key < kb[pix]) atomicMin(&kb[pix], key);
        }
}

__global__ void resolve_flat(const unsigned long long* __restrict__ kb,
                             const float* __restrict__ vox, float* __restrict__ out) {
    int p = blockIdx.x * blockDim.x + threadIdx.x;
    if (p >= NPIX) return;
    unsigned long long key = kb[p];
    float r = 0.0f, g = 0.0f, b = 0.0f;
    if (key != EMPTY_KEY) {
        unsigned n = (unsigned)(key & 0xFFFFFFFFull) / 9u;
        r = vox[n*6+3]; g = vox[n*6+4]; b = vox[n*6+5];
    }
    out[p*3+0] = r; out[p*3+1] = g; out[p*3+2] = b;
}

extern "C" void kernel_launch(void* const* d_in, const int* in_sizes, int n_in,
                              void* d_out, int out_size, void* d_ws, size_t ws_size,
                              hipStream_t stream) {
    const float* vox = (const float*)d_in[0];
    const float* m1  = (const float*)d_in[1];
    const float* m2  = (const float*)d_in[2];
    float* out = (float*)d_out;
    int N = in_sizes[0] / 6;

    if (ws_size >= (size_t)NSHARD * NPIX * sizeof(unsigned long long)) {
        unsigned long long* shards = (unsigned long long*)d_ws;   // 16 MB
        init_shards<<<(NSHARD * NPIX + 255) / 256, 256, 0, stream>>>(shards);
        splat_sharded<<<(N + 255) / 256, 256, 0, stream>>>(vox, m1, m2, shards, N);
        merge_resolve<<<(NPIX + 255) / 256, 256, 0, stream>>>(shards, vox, out);
    } else {
        unsigned long long* kb = (unsigned long long*)d_ws;       // 2 MB
        init_bufs<<<(NPIX + 255) / 256, 256, 0, stream>>>(kb);
        splat_flat<<<(N + 255) / 256, 256, 0, stream>>>(vox, m1, m2, kb, N);
        resolve_flat<<<(NPIX + 255) / 256, 256, 0, stream>>>(kb, vox, out);
    }
}

// Round 16
// 100.459 us; speedup vs baseline: 2.2797x; 2.2797x over previous
//
#include <hip/hip_runtime.h>

#define IW 512
#define IH 512
#define NPIX (IW * IH)
#define EMPTY_KEY 0xFFFFFFFFFFFFFFFFull

__global__ void init_bufs(unsigned long long* __restrict__ kb) {
    int i = blockIdx.x * blockDim.x + threadIdx.x;
    if (i < NPIX) kb[i] = EMPTY_KEY;
}

__global__ void snap_copy(const unsigned long long* __restrict__ kb,
                          unsigned long long* __restrict__ snap) {
    int i = blockIdx.x * blockDim.x + threadIdx.x;
    if (i < NPIX) snap[i] = kb[i];
}

// f32 mirror of the XLA-on-gfx950 compiled reference graph (FROZEN — passed
// absmax 0.0 in rounds 8-15):
//  - divisions lowered as a * v_rcp_f32(b)
//  - r2 contracted as fma(dx,dx, dy*dy)
//  - all other ops singly-rounded (contract(off)); matmul terms exact.
__device__ __forceinline__ bool project_voxel(
        float x, float y, float z0,
        const float* __restrict__ m1, const float* __restrict__ m2,
        float& px, float& py, float& vz) {
#pragma clang fp contract(off)
    float vh0 = ((x * m1[0]  + y * m1[4])  + z0 * m1[8])  + m1[12];
    float vh1 = ((x * m1[1]  + y * m1[5])  + z0 * m1[9])  + m1[13];
    float vh2 = ((x * m1[2]  + y * m1[6])  + z0 * m1[10]) + m1[14];
    float vh3 = ((x * m1[3]  + y * m1[7])  + z0 * m1[11]) + m1[15];

    float wv  = (fabsf(vh3) > 1e-8f) ? vh3 : 1.0f;
    float rwv = __builtin_amdgcn_rcpf(wv);
    float vx  = vh0 * rwv;
    float vy  = vh1 * rwv;
    vz        = vh2 * rwv;

    float cl0 = ((vx * m2[0] + vy * m2[4]) + vz * m2[8])  + m2[12];
    float cl1 = ((vx * m2[1] + vy * m2[5]) + vz * m2[9])  + m2[13];
    float cl3 = ((vx * m2[3] + vy * m2[7]) + vz * m2[11]) + m2[15];

    if (!(fabsf(cl3) > 1e-8f)) return false;  // valid: |w| > 1e-8 (rejects NaN)
    if (!(vz > 1e-6f)) return false;          // valid: z > 1e-6  (rejects NaN)

    float rw   = __builtin_amdgcn_rcpf(cl3);
    float ndcx = cl0 * rw;
    float ndcy = cl1 * rw;
    px = ((ndcx + 1.0f) * 0.5f) * (float)IW;
    py = ((ndcy + 1.0f) * 0.5f) * (float)IH;
    return true;
}

// Lexicographic min over packed (zbits<<32 | pid).
//  SNAP=0: blind atomicMin (write-side only; used for the converging prefix).
//  SNAP=1: pre-check against a READ-ONLY snapshot (L2/L3-resident, never
//          invalidated), then blind atomicMin on the live kb.
// Safety: keys at a pixel only decrease; snap holds a value kb actually
// held, so key >= snap[pix] >= kb_final[pix] -> skipping cannot drop a
// winner. Min is order-invariant -> bit-exact regardless of phase split.
template <int SNAP>
__global__ __launch_bounds__(256) void splat(
        const float* __restrict__ vox, const float* __restrict__ m1,
        const float* __restrict__ m2,
        const unsigned long long* __restrict__ snap,
        unsigned long long* __restrict__ kb,
        int n0, int n1) {
#pragma clang fp contract(off)
    int n = n0 + blockIdx.x * blockDim.x + threadIdx.x;
    if (n >= n1) return;

    float x  = vox[n * 6 + 0];
    float y  = vox[n * 6 + 1];
    float z0 = vox[n * 6 + 2];

    float px, py, vz;
    if (!project_voxel(x, y, z0, m1, m2, px, py, vz)) return;

    float fx = floorf(px);
    float fy = floorf(py);
    if (!(fx >= -1.0f && fx <= (float)IW && fy >= -1.0f && fy <= (float)IH))
        return;

    unsigned long long zhi = ((unsigned long long)__float_as_uint(vz)) << 32;
    unsigned basepid = (unsigned)n * 9u;

    for (int oy = -1; oy <= 1; ++oy) {
        for (int ox = -1; ox <= 1; ++ox) {
            float ixf = fx + (float)ox;
            float iyf = fy + (float)oy;
            if (!(ixf >= 0.0f && ixf < (float)IW &&
                  iyf >= 0.0f && iyf < (float)IH)) continue;
            float dx = (ixf + 0.5f) - px;
            float dy = (iyf + 0.5f) - py;
            float r2 = fmaf(dx, dx, dy * dy);   // frozen contraction form
            if (!(r2 <= 1.0f)) continue;
            int pix = (int)iyf * IW + (int)ixf;
            unsigned pid = basepid + (unsigned)((oy + 1) * 3 + (ox + 1));
            unsigned long long key = zhi | (unsigned long long)pid;
            if (SNAP) {
                if (key < snap[pix])            // read-only, cache-resident
                    atomicMin(&kb[pix], key);   // blind — no live-line load
            } else {
                atomicMin(&kb[pix], key);       // blind
            }
        }
    }
}

__global__ void resolve(const unsigned long long* __restrict__ kb,
                        const float* __restrict__ vox,
                        float* __restrict__ out) {
    int p = blockIdx.x * blockDim.x + threadIdx.x;
    if (p >= NPIX) return;
    unsigned long long key = kb[p];
    float r = 0.0f, g = 0.0f, b = 0.0f;
    if (key != EMPTY_KEY) {
        unsigned pid = (unsigned)(key & 0xFFFFFFFFull);
        unsigned n = pid / 9u;
        r = vox[n * 6 + 3];
        g = vox[n * 6 + 4];
        b = vox[n * 6 + 5];
    }
    out[p * 3 + 0] = r;
    out[p * 3 + 1] = g;
    out[p * 3 + 2] = b;
}

extern "C" void kernel_launch(void* const* d_in, const int* in_sizes, int n_in,
                              void* d_out, int out_size, void* d_ws, size_t ws_size,
                              hipStream_t stream) {
    const float* vox = (const float*)d_in[0];
    const float* m1  = (const float*)d_in[1];
    const float* m2  = (const float*)d_in[2];
    float* out = (float*)d_out;
    int N = in_sizes[0] / 6;

    unsigned long long* kb   = (unsigned long long*)d_ws;   // 2 MB
    unsigned long long* snap = kb + NPIX;                   // 2 MB

    const int pixblocks = (NPIX + 255) / 256;
    init_bufs<<<pixblocks, 256, 0, stream>>>(kb);

    if (ws_size >= 2ull * NPIX * sizeof(unsigned long long)) {
        // 3-stage snapshot ladder: issued atomics ~1.75M vs r13's 2.6M.
        int nA = N / 8;        // blind converging prefix
        int nB = 3 * (N / 8);  // mid stage boundary
        splat<0><<<(nA + 255) / 256, 256, 0, stream>>>(
            vox, m1, m2, nullptr, kb, 0, nA);
        snap_copy<<<pixblocks, 256, 0, stream>>>(kb, snap);
        splat<1><<<((nB - nA) + 255) / 256, 256, 0, stream>>>(
            vox, m1, m2, snap, kb, nA, nB);
        snap_copy<<<pixblocks, 256, 0, stream>>>(kb, snap);   // fresher snap
        splat<1><<<((N - nB) + 255) / 256, 256, 0, stream>>>(
            vox, m1, m2, snap, kb, nB, N);
    } else {
        // minimal-ws fallback: single blind pass (round-8 style, proven)
        splat<0><<<(N + 255) / 256, 256, 0, stream>>>(
            vox, m1, m2, nullptr, kb, 0, N);
    }

    resolve<<<pixblocks, 256, 0, stream>>>(kb, vox, out);
}

// Round 17
// 99.377 us; speedup vs baseline: 2.3045x; 1.0109x over previous
//
#include <hip/hip_runtime.h>

#define IW 512
#define IH 512
#define NPIX (IW * IH)
#define EMPTY_KEY 0xFFFFFFFFFFFFFFFFull

__global__ void init_bufs(unsigned long long* __restrict__ kb) {
    int i = blockIdx.x * blockDim.x + threadIdx.x;
    if (i < NPIX) kb[i] = EMPTY_KEY;
}

__global__ void snap_copy(const unsigned long long* __restrict__ kb,
                          unsigned long long* __restrict__ snap) {
    int i = blockIdx.x * blockDim.x + threadIdx.x;
    if (i < NPIX) snap[i] = kb[i];
}

// f32 mirror of the XLA-on-gfx950 compiled reference graph (FROZEN — passed
// absmax 0.0 in rounds 8-16):
//  - divisions lowered as a * v_rcp_f32(b)
//  - r2 contracted as fma(dx,dx, dy*dy)
//  - all other ops singly-rounded (contract(off)); matmul terms exact.
__device__ __forceinline__ bool project_voxel(
        float x, float y, float z0,
        const float* __restrict__ m1, const float* __restrict__ m2,
        float& px, float& py, float& vz) {
#pragma clang fp contract(off)
    float vh0 = ((x * m1[0]  + y * m1[4])  + z0 * m1[8])  + m1[12];
    float vh1 = ((x * m1[1]  + y * m1[5])  + z0 * m1[9])  + m1[13];
    float vh2 = ((x * m1[2]  + y * m1[6])  + z0 * m1[10]) + m1[14];
    float vh3 = ((x * m1[3]  + y * m1[7])  + z0 * m1[11]) + m1[15];

    float wv  = (fabsf(vh3) > 1e-8f) ? vh3 : 1.0f;
    float rwv = __builtin_amdgcn_rcpf(wv);
    float vx  = vh0 * rwv;
    float vy  = vh1 * rwv;
    vz        = vh2 * rwv;

    float cl0 = ((vx * m2[0] + vy * m2[4]) + vz * m2[8])  + m2[12];
    float cl1 = ((vx * m2[1] + vy * m2[5]) + vz * m2[9])  + m2[13];
    float cl3 = ((vx * m2[3] + vy * m2[7]) + vz * m2[11]) + m2[15];

    if (!(fabsf(cl3) > 1e-8f)) return false;  // valid: |w| > 1e-8 (rejects NaN)
    if (!(vz > 1e-6f)) return false;          // valid: z > 1e-6  (rejects NaN)

    float rw   = __builtin_amdgcn_rcpf(cl3);
    float ndcx = cl0 * rw;
    float ndcy = cl1 * rw;
    px = ((ndcx + 1.0f) * 0.5f) * (float)IW;
    py = ((ndcy + 1.0f) * 0.5f) * (float)IH;
    return true;
}

// Lexicographic min over packed (zbits<<32 | pid).
//  SNAP=0: blind atomicMin (converging prefix — write side only).
//  SNAP=1: pre-check against a READ-ONLY snapshot (cache-resident, never
//          invalidated), then blind atomicMin on the live kb.
// Safety: keys at a pixel only decrease; snap holds a value kb actually
// held, so key >= snap[pix] >= kb_final[pix] -> skipping cannot drop a
// winner. Min is order-invariant -> bit-exact for any stage split.
template <int SNAP>
__global__ __launch_bounds__(256) void splat(
        const float* __restrict__ vox, const float* __restrict__ m1,
        const float* __restrict__ m2,
        const unsigned long long* __restrict__ snap,
        unsigned long long* __restrict__ kb,
        int n0, int n1) {
#pragma clang fp contract(off)
    int n = n0 + blockIdx.x * blockDim.x + threadIdx.x;
    if (n >= n1) return;

    float x  = vox[n * 6 + 0];
    float y  = vox[n * 6 + 1];
    float z0 = vox[n * 6 + 2];

    float px, py, vz;
    if (!project_voxel(x, y, z0, m1, m2, px, py, vz)) return;

    float fx = floorf(px);
    float fy = floorf(py);
    if (!(fx >= -1.0f && fx <= (float)IW && fy >= -1.0f && fy <= (float)IH))
        return;

    unsigned long long zhi = ((unsigned long long)__float_as_uint(vz)) << 32;
    unsigned basepid = (unsigned)n * 9u;

    for (int oy = -1; oy <= 1; ++oy) {
        for (int ox = -1; ox <= 1; ++ox) {
            float ixf = fx + (float)ox;
            float iyf = fy + (float)oy;
            if (!(ixf >= 0.0f && ixf < (float)IW &&
                  iyf >= 0.0f && iyf < (float)IH)) continue;
            float dx = (ixf + 0.5f) - px;
            float dy = (iyf + 0.5f) - py;
            float r2 = fmaf(dx, dx, dy * dy);   // frozen contraction form
            if (!(r2 <= 1.0f)) continue;
            int pix = (int)iyf * IW + (int)ixf;
            unsigned pid = basepid + (unsigned)((oy + 1) * 3 + (ox + 1));
            unsigned long long key = zhi | (unsigned long long)pid;
            if (SNAP) {
                if (key < snap[pix])            // read-only, cache-resident
                    atomicMin(&kb[pix], key);   // blind — no live-line load
            } else {
                atomicMin(&kb[pix], key);       // blind
            }
        }
    }
}

__global__ void resolve(const unsigned long long* __restrict__ kb,
                        const float* __restrict__ vox,
                        float* __restrict__ out) {
    int p = blockIdx.x * blockDim.x + threadIdx.x;
    if (p >= NPIX) return;
    unsigned long long key = kb[p];
    float r = 0.0f, g = 0.0f, b = 0.0f;
    if (key != EMPTY_KEY) {
        unsigned pid = (unsigned)(key & 0xFFFFFFFFull);
        unsigned n = pid / 9u;
        r = vox[n * 6 + 3];
        g = vox[n * 6 + 4];
        b = vox[n * 6 + 5];
    }
    __builtin_nontemporal_store(r, out + p * 3 + 0);
    __builtin_nontemporal_store(g, out + p * 3 + 1);
    __builtin_nontemporal_store(b, out + p * 3 + 2);
}

extern "C" void kernel_launch(void* const* d_in, const int* in_sizes, int n_in,
                              void* d_out, int out_size, void* d_ws, size_t ws_size,
                              hipStream_t stream) {
    const float* vox = (const float*)d_in[0];
    const float* m1  = (const float*)d_in[1];
    const float* m2  = (const float*)d_in[2];
    float* out = (float*)d_out;
    int N = in_sizes[0] / 6;

    unsigned long long* kb   = (unsigned long long*)d_ws;   // 2 MB
    unsigned long long* snap = kb + NPIX;                   // 2 MB

    const int pixblocks = (NPIX + 255) / 256;
    init_bufs<<<pixblocks, 256, 0, stream>>>(kb);

    if (ws_size >= 2ull * NPIX * sizeof(unsigned long long)) {
        // 4-stage snapshot ladder (boundaries 1/32, 1/8, 3/8, 1):
        // per-pixel issued atomics ~5.0 vs r16's 6.5 (model: (b-a)T/(aT+1)).
        int n1 = N / 32;
        int n2 = N / 8;
        int n3 = 3 * (N / 8);
        splat<0><<<(n1 + 255) / 256, 256, 0, stream>>>(
            vox, m1, m2, nullptr, kb, 0, n1);
        snap_copy<<<pixblocks, 256, 0, stream>>>(kb, snap);
        splat<1><<<((n2 - n1) + 255) / 256, 256, 0, stream>>>(
            vox, m1, m2, snap, kb, n1, n2);
        snap_copy<<<pixblocks, 256, 0, stream>>>(kb, snap);
        splat<1><<<((n3 - n2) + 255) / 256, 256, 0, stream>>>(
            vox, m1, m2, snap, kb, n2, n3);
        snap_copy<<<pixblocks, 256, 0, stream>>>(kb, snap);
        splat<1><<<((N - n3) + 255) / 256, 256, 0, stream>>>(
            vox, m1, m2, snap, kb, n3, N);
    } else {
        // minimal-ws fallback: single blind pass (round-8 style, proven)
        splat<0><<<(N + 255) / 256, 256, 0, stream>>>(
            vox, m1, m2, nullptr, kb, 0, N);
    }

    resolve<<<pixblocks, 256, 0, stream>>>(kb, vox, out);
}